// Round 1
// baseline (333.127 us; speedup 1.0000x reference)
//
#include <hip/hip_runtime.h>
#include <hip/hip_bf16.h>
#include <math.h>

#define N_NODES 50000
#define N_EDGES 800000
#define N_GRAPHS 64
#define HID 128
#define N_CLASSES 10
#define N_LAYERS 3
#define NEG_SLOPE 0.2f

#define NB 196        // dst buckets of 256 nodes
#define BCAP 5120     // slots per bucket (mean ~4337, sigma ~66 -> +12 sigma)
#define ACHUNK 4096   // edges per partition block

typedef __attribute__((ext_vector_type(8))) short short8;
typedef __attribute__((ext_vector_type(4))) float f32x4;
typedef __attribute__((ext_vector_type(2))) _Float16 h2;

extern "C" __device__ _Float16 __ocml_exp2_f16(_Float16);

__device__ inline ushort f2bf(float f) {
    uint u = __builtin_bit_cast(uint, f);
    u += 0x7fffu + ((u >> 16) & 1u);      // RNE
    return (ushort)(u >> 16);
}
__device__ inline uint pk2bf(float a, float b) {
    return (uint)f2bf(a) | ((uint)f2bf(b) << 16);
}
__device__ inline h2 pkh(float a, float b) {
    return __builtin_bit_cast(h2, __builtin_amdgcn_cvt_pkrtz(a, b));
}

// ---------------- setup: x/W bf16 prep + edge partition, one launch ----------------

__global__ __launch_bounds__(256) void setup_kernel(
    const float* __restrict__ x, uint* __restrict__ xb, int n,
    const float* __restrict__ Wl, const float* __restrict__ Wr,
    uint* __restrict__ wt, int wtot,
    const int* __restrict__ ei, int E,
    int* __restrict__ bptr, uint* __restrict__ bbuf,
    int xqb, int wb) {
    __shared__ int hcnt[256];
    __shared__ int hexcl[256];
    __shared__ int lofs[256];
    __shared__ int delta[256];
    __shared__ uint stage[ACHUNK];
    int t = threadIdx.x;
    int blk = blockIdx.x;

    if (blk < xqb) {                      // ---- x prep: 1 uint4 (8 floats) per thread
        int j = blk * 256 + t;
        if (j < n * 16) {
            const float4* xp = (const float4*)x + (size_t)j * 2;
            float4 a = xp[0], b = xp[1];
            uint4 o;
            o.x = pk2bf(a.x, a.y); o.y = pk2bf(a.z, a.w);
            o.z = pk2bf(b.x, b.y); o.w = pk2bf(b.z, b.w);
            ((uint4*)xb)[j] = o;
        }
        return;
    }
    blk -= xqb;
    if (blk < wb) {                       // ---- W prep (bf16)
        int i = blk * 256 + t;
        if (i >= wtot) return;
        int kp = i & 63;
        int nn = (i >> 6) & 255;
        int l  = i >> 14;
        const float* W = (nn < 128) ? Wl : Wr;
        int c = nn & 127;
        wt[i] = pk2bf(W[l * 16384 + (2 * kp) * 128 + c],
                      W[l * 16384 + (2 * kp + 1) * 128 + c]);
        return;
    }
    blk -= wb;                            // ---- partition
    int total = E + n;
    int base = blk * ACHUNK;
    int cntblk = min(ACHUNK, total - base);
    hcnt[t] = 0; lofs[t] = 0;
    __syncthreads();

    uint v[16]; int bk[16];
#pragma unroll
    for (int j = 0; j < 16; ++j) {
        int e = base + j * 256 + t;
        bk[j] = -1;
        if (e < total) {
            int s, d;
            if (e < E) { s = ei[e]; d = ei[E + e]; }
            else       { s = e - E; d = e - E; }
            v[j] = ((uint)s << 16) | (uint)d;    // src,dst both < 65536
            bk[j] = d >> 8;
            atomicAdd(&hcnt[bk[j]], 1);
        }
    }
    __syncthreads();
    int hv = hcnt[t];
    __shared__ int stmp[256];
    stmp[t] = hv;
    __syncthreads();
    for (int off = 1; off < 256; off <<= 1) {
        int u = (t >= off) ? stmp[t - off] : 0;
        __syncthreads();
        stmp[t] += u;
        __syncthreads();
    }
    hexcl[t] = stmp[t] - hv;
    __syncthreads();
#pragma unroll
    for (int j = 0; j < 16; ++j) {
        if (bk[j] >= 0) {
            int pos = hexcl[bk[j]] + atomicAdd(&lofs[bk[j]], 1);
            stage[pos] = v[j];
        }
    }
    __syncthreads();
    if (t < NB) {
        int c = hcnt[t];
        int gb = c ? atomicAdd(&bptr[t], c) : 0;
        delta[t] = t * BCAP + gb - hexcl[t];
    }
    __syncthreads();
    for (int idx = t; idx < cntblk; idx += 256) {
        uint val = stage[idx];
        int b = (val >> 8) & 0xff;
        int tgt = delta[b] + idx;
        if (tgt < (b + 1) * BCAP) bbuf[tgt] = val;
    }
}

// ---------------- bucket CSR (blocks 0..NB) + gemm layer 0 (rest), one launch --------
// gemm inputs A,W stay bf16; OUTPUT xl/xr is fp16 (consumed only by attn).

__device__ __forceinline__ void gemm_body(
    const ushort* __restrict__ A, const ushort* __restrict__ Wt,
    const float* __restrict__ bl, const float* __restrict__ br,
    ushort* __restrict__ xlb, ushort* __restrict__ xrb, int n, int bid, int tid) {
    int wv = tid >> 6;
    int lane = tid & 63;
    int q = lane >> 4, m16 = lane & 15;
    int m0 = bid * 64;

    short8 bf[4][4];
#pragma unroll
    for (int nt = 0; nt < 4; ++nt) {
        const ushort* wp = Wt + (size_t)(wv * 64 + nt * 16 + m16) * 128 + q * 8;
#pragma unroll
        for (int ks = 0; ks < 4; ++ks) bf[nt][ks] = *(const short8*)(wp + ks * 32);
    }
    const ushort* ap[4];
#pragma unroll
    for (int mt = 0; mt < 4; ++mt) {
        int r = m0 + mt * 16 + m16;
        if (r > n - 1) r = n - 1;
        ap[mt] = A + (size_t)r * 128 + q * 8;
    }

    f32x4 z = {0.f, 0.f, 0.f, 0.f};
    f32x4 acc[4][4];
#pragma unroll
    for (int mt = 0; mt < 4; ++mt)
#pragma unroll
        for (int nt = 0; nt < 4; ++nt) acc[mt][nt] = z;

#pragma unroll
    for (int ks = 0; ks < 4; ++ks) {
        short8 af[4];
#pragma unroll
        for (int mt = 0; mt < 4; ++mt) af[mt] = *(const short8*)(ap[mt] + ks * 32);
#pragma unroll
        for (int mt = 0; mt < 4; ++mt)
#pragma unroll
            for (int nt = 0; nt < 4; ++nt)
                acc[mt][nt] = __builtin_amdgcn_mfma_f32_16x16x32_bf16(
                    bf[nt][ks], af[mt], acc[mt][nt], 0, 0, 0);
    }

    ushort* outp = (wv >= 2) ? xrb : xlb;
    const float* bx = (wv >= 2) ? br : bl;
    int fb = (wv & 1) * 64;
#pragma unroll
    for (int nt = 0; nt < 4; ++nt) {
        int fcol = fb + nt * 16 + q * 4;
        float4 b4 = *(const float4*)&bx[fcol];
#pragma unroll
        for (int mt = 0; mt < 4; ++mt) {
            int m = m0 + mt * 16 + m16;
            if (m < n) {
                uint2 pk;
                pk.x = __builtin_bit_cast(uint, pkh(acc[mt][nt][0] + b4.x,
                                                    acc[mt][nt][1] + b4.y));
                pk.y = __builtin_bit_cast(uint, pkh(acc[mt][nt][2] + b4.z,
                                                    acc[mt][nt][3] + b4.w));
                *(uint2*)&outp[(size_t)m * 128 + fcol] = pk;
            }
        }
    }
}

__global__ __launch_bounds__(256) void csr_gemm0_kernel(
    const int* __restrict__ bptr, const uint* __restrict__ bbuf, int n,
    int* __restrict__ row_start, int* __restrict__ ssrc,
    const ushort* __restrict__ A, const ushort* __restrict__ Wt,
    const float* __restrict__ bl, const float* __restrict__ br,
    ushort* __restrict__ xlb, ushort* __restrict__ xrb) {
    int t = threadIdx.x;
    if (blockIdx.x >= NB) {
        gemm_body(A, Wt, bl, br, xlb, xrb, n, blockIdx.x - NB, t);
        return;
    }
    int b = blockIdx.x;
    __shared__ int sb[256], h[256], hx[256], lofs[256];
    int bv = (t < NB) ? min(bptr[t], BCAP) : 0;
    sb[t] = bv;
    __syncthreads();
    for (int off = 1; off < 256; off <<= 1) {
        int u = (t >= off) ? sb[t - off] : 0;
        __syncthreads();
        sb[t] += u;
        __syncthreads();
    }
    int cnt = min(bptr[b], BCAP);
    int base = sb[b] - cnt;               // exclusive prefix
    if (b == NB - 1 && t == 0) row_start[n] = sb[NB - 1];
    h[t] = 0; lofs[t] = 0;
    __syncthreads();
    const uint* bp = bbuf + (size_t)b * BCAP;
    for (int k = t; k < cnt; k += 256) atomicAdd(&h[bp[k] & 255u], 1);
    __syncthreads();
    int hv = h[t];
    hx[t] = hv;
    __syncthreads();
    for (int off = 1; off < 256; off <<= 1) {
        int u = (t >= off) ? hx[t - off] : 0;
        __syncthreads();
        hx[t] += u;
        __syncthreads();
    }
    int excl = hx[t] - hv;
    int node = (b << 8) + t;
    if (node < n) row_start[node] = base + excl;
    __syncthreads();
    h[t] = excl;
    __syncthreads();
    for (int k = t; k < cnt; k += 256) {
        uint val = bp[k];
        int dl = val & 255u;
        int pos = base + h[dl] + atomicAdd(&lofs[dl], 1);
        ssrc[pos] = (int)((val & 0xffff0000u) >> 8);   // src*256 byte offset
    }
}

__global__ __launch_bounds__(256) void gemm_mfma(
    const ushort* __restrict__ A, const ushort* __restrict__ Wt,
    const float* __restrict__ bl, const float* __restrict__ br,
    ushort* __restrict__ xlb, ushort* __restrict__ xrb, int n) {
    gemm_body(A, Wt, bl, br, xlb, xrb, n, blockIdx.x, threadIdx.x);
}

// ---------------- fused attention: 16-lane/edge datapath, 4 edge groups per wave ------
// xl/xr fp16 pairs; lane holds 8 channels (uint4). Scores carry the built-in -8 shift
// (EINIT -1/half-pair per lane, 4-lane head sum) so exp2 weights stay small and f16
// den/acc cannot overflow; the 2^-8 cancels in the softmax division.
// vs previous 32-lane/edge version: VMEM issues per 16 edges 16 -> 6, head-sum
// shuffle tree 3 levels -> 2 (quad-perm DPP only, no DS swizzle in the hot loop).

#define SLOTE4(u, v01, v23, v45, v67, eh)                  \
    h2 v01 = __builtin_bit_cast(h2, u.x);                  \
    h2 v23 = __builtin_bit_cast(h2, u.y);                  \
    h2 v45 = __builtin_bit_cast(h2, u.z);                  \
    h2 v67 = __builtin_bit_cast(h2, u.w);                  \
    h2 eh;                                                 \
    {                                                      \
        h2 t01 = v01 + xr01, t23 = v23 + xr23;             \
        h2 t45 = v45 + xr45, t67 = v67 + xr67;             \
        t01 = __builtin_elementwise_max(t01, t01 * K02);   \
        t23 = __builtin_elementwise_max(t23, t23 * K02);   \
        t45 = __builtin_elementwise_max(t45, t45 * K02);   \
        t67 = __builtin_elementwise_max(t67, t67 * K02);   \
        eh = EINIT + at01 * t01;                           \
        eh += at23 * t23;                                  \
        eh += at45 * t45;                                  \
        eh += at67 * t67;                                  \
    }

__device__ inline uint packpair(h2 a, h2 b) {   // -> (a.x+a.y, b.x+b.y)
    h2 lo = {a.x, b.x};
    h2 hi = {a.y, b.y};
    return __builtin_bit_cast(uint, lo + hi);
}
__device__ inline uint shfl_add_h2(uint q, int m) {
    uint r = (uint)__shfl_xor((int)q, m);
    h2 s = __builtin_bit_cast(h2, q) + __builtin_bit_cast(h2, r);
    return __builtin_bit_cast(uint, s);
}

__global__ __launch_bounds__(256) void attn_kernel(
    const uint* __restrict__ xlb, const uint* __restrict__ xrb,
    const float* __restrict__ att, const float* __restrict__ bias,
    const int* __restrict__ row_start, const int* __restrict__ ssrc,
    uint* __restrict__ hout, int n) {
    int wave = threadIdx.x >> 6;
    int lane = threadIdx.x & 63;
    int g    = lane >> 4;          // edge group 0..3
    int l16  = lane & 15;          // channel-slice lane: ch 8*l16 .. 8*l16+7
    int i = blockIdx.x * 4 + wave;
    if (i >= n) return;

    const char* xlB = (const char*)xlb;
    uint lofs = (uint)l16 * 16;

    uint4 xru = *(const uint4*)((const char*)xrb + (size_t)i * 256 + lofs);
    h2 xr01 = __builtin_bit_cast(h2, xru.x);
    h2 xr23 = __builtin_bit_cast(h2, xru.y);
    h2 xr45 = __builtin_bit_cast(h2, xru.z);
    h2 xr67 = __builtin_bit_cast(h2, xru.w);
    const float L2E = 1.4426950408889634f;
    float4 atA = ((const float4*)att)[l16 * 2];
    float4 atB = ((const float4*)att)[l16 * 2 + 1];
    h2 at01 = pkh(atA.x * L2E, atA.y * L2E);
    h2 at23 = pkh(atA.z * L2E, atA.w * L2E);
    h2 at45 = pkh(atB.x * L2E, atB.y * L2E);
    h2 at67 = pkh(atB.z * L2E, atB.w * L2E);
    const h2 K02   = {(_Float16)0.2f, (_Float16)0.2f};
    const h2 EINIT = {(_Float16)-1.0f, (_Float16)-1.0f};   // -2/lane * 4 lanes = -8

    int p0 = row_start[i], p1 = row_start[i + 1];

    h2 denP = {0, 0};
    h2 aA01 = {0, 0}, aA23 = {0, 0}, aA45 = {0, 0}, aA67 = {0, 0};  // even slots
    h2 aB01 = {0, 0}, aB23 = {0, 0}, aB45 = {0, 0}, aB67 = {0, 0};  // odd slots

    int p = p0;
    for (; p + 16 <= p1; p += 16) {        // 16 edges: 4 slots x 4 groups
        uint s0 = (uint)ssrc[p + g];
        uint s1 = (uint)ssrc[p + 4 + g];
        uint s2 = (uint)ssrc[p + 8 + g];
        uint s3 = (uint)ssrc[p + 12 + g];
        uint4 u0 = *(const uint4*)(xlB + s0 + lofs);
        uint4 u1 = *(const uint4*)(xlB + s1 + lofs);
        uint4 u2 = *(const uint4*)(xlB + s2 + lofs);
        uint4 u3 = *(const uint4*)(xlB + s3 + lofs);
        SLOTE4(u0, v001, v023, v045, v067, eh0);
        SLOTE4(u1, v101, v123, v145, v167, eh1);
        SLOTE4(u2, v201, v223, v245, v267, eh2);
        SLOTE4(u3, v301, v323, v345, v367, eh3);
        uint q01 = packpair(eh0, eh1);
        uint q23 = packpair(eh2, eh3);
        q01 = shfl_add_h2(q01, 1); q23 = shfl_add_h2(q23, 1);
        q01 = shfl_add_h2(q01, 2); q23 = shfl_add_h2(q23, 2);
        h2 e01 = __builtin_bit_cast(h2, q01);
        h2 e23 = __builtin_bit_cast(h2, q23);
        h2 w01, w23;
        w01.x = __ocml_exp2_f16(e01.x); w01.y = __ocml_exp2_f16(e01.y);
        w23.x = __ocml_exp2_f16(e23.x); w23.y = __ocml_exp2_f16(e23.y);
        denP += w01; denP += w23;
        h2 wA = {w01.x, w01.x}, wB = {w01.y, w01.y};
        h2 wC = {w23.x, w23.x}, wD = {w23.y, w23.y};
        aA01 += wA * v001; aA23 += wA * v023; aA45 += wA * v045; aA67 += wA * v067;
        aB01 += wB * v101; aB23 += wB * v123; aB45 += wB * v145; aB67 += wB * v167;
        aA01 += wC * v201; aA23 += wC * v223; aA45 += wC * v245; aA67 += wC * v267;
        aB01 += wD * v301; aB23 += wD * v323; aB45 += wD * v345; aB67 += wD * v367;
    }
    for (; p + 8 <= p1; p += 8) {          // 8 edges: 2 slots x 4 groups
        uint s0 = (uint)ssrc[p + g];
        uint s1 = (uint)ssrc[p + 4 + g];
        uint4 u0 = *(const uint4*)(xlB + s0 + lofs);
        uint4 u1 = *(const uint4*)(xlB + s1 + lofs);
        SLOTE4(u0, v001, v023, v045, v067, eh0);
        SLOTE4(u1, v101, v123, v145, v167, eh1);
        uint q01 = packpair(eh0, eh1);
        q01 = shfl_add_h2(q01, 1);
        q01 = shfl_add_h2(q01, 2);
        h2 e01 = __builtin_bit_cast(h2, q01);
        h2 w01;
        w01.x = __ocml_exp2_f16(e01.x); w01.y = __ocml_exp2_f16(e01.y);
        denP += w01;
        h2 wA = {w01.x, w01.x}, wB = {w01.y, w01.y};
        aA01 += wA * v001; aA23 += wA * v023; aA45 += wA * v045; aA67 += wA * v067;
        aB01 += wB * v101; aB23 += wB * v123; aB45 += wB * v145; aB67 += wB * v167;
    }
    if (p < p1) {                           // masked epilogue: 1..7 edges
        int lst = p1 - 1;
        int i0 = p + g, i1 = p + 4 + g;
        uint s0 = (uint)ssrc[min(i0, lst)];
        uint s1 = (uint)ssrc[min(i1, lst)];
        uint4 u0 = *(const uint4*)(xlB + s0 + lofs);
        uint4 u1 = *(const uint4*)(xlB + s1 + lofs);
        SLOTE4(u0, v001, v023, v045, v067, eh0);
        SLOTE4(u1, v101, v123, v145, v167, eh1);
        uint q01 = packpair(eh0, eh1);
        q01 = shfl_add_h2(q01, 1);
        q01 = shfl_add_h2(q01, 2);
        h2 e01 = __builtin_bit_cast(h2, q01);
        h2 w01;
        const _Float16 zh = (_Float16)0.f;
        w01.x = (i0 < p1) ? __ocml_exp2_f16(e01.x) : zh;
        w01.y = (i1 < p1) ? __ocml_exp2_f16(e01.y) : zh;
        denP += w01;
        h2 wA = {w01.x, w01.x}, wB = {w01.y, w01.y};
        aA01 += wA * v001; aA23 += wA * v023; aA45 += wA * v045; aA67 += wA * v067;
        aB01 += wB * v101; aB23 += wB * v123; aB45 += wB * v145; aB67 += wB * v167;
    }

    // cross-group (masks 16, 32) reduce in f32, once per node
    float den = (float)denP.x + (float)denP.y;
    float a0 = (float)(_Float16)(aA01.x + aB01.x);
    float a1 = (float)(_Float16)(aA01.y + aB01.y);
    float a2 = (float)(_Float16)(aA23.x + aB23.x);
    float a3 = (float)(_Float16)(aA23.y + aB23.y);
    float a4 = (float)(_Float16)(aA45.x + aB45.x);
    float a5 = (float)(_Float16)(aA45.y + aB45.y);
    float a6 = (float)(_Float16)(aA67.x + aB67.x);
    float a7 = (float)(_Float16)(aA67.y + aB67.y);
    den += __shfl_xor(den, 16); den += __shfl_xor(den, 32);
    a0 += __shfl_xor(a0, 16); a0 += __shfl_xor(a0, 32);
    a1 += __shfl_xor(a1, 16); a1 += __shfl_xor(a1, 32);
    a2 += __shfl_xor(a2, 16); a2 += __shfl_xor(a2, 32);
    a3 += __shfl_xor(a3, 16); a3 += __shfl_xor(a3, 32);
    a4 += __shfl_xor(a4, 16); a4 += __shfl_xor(a4, 32);
    a5 += __shfl_xor(a5, 16); a5 += __shfl_xor(a5, 32);
    a6 += __shfl_xor(a6, 16); a6 += __shfl_xor(a6, 32);
    a7 += __shfl_xor(a7, 16); a7 += __shfl_xor(a7, 32);

    if (g == 0) {
        float inv = 1.f / den;
        float4 biA = ((const float4*)bias)[l16 * 2];
        float4 biB = ((const float4*)bias)[l16 * 2 + 1];
        float o0 = a0 * inv + biA.x; o0 = o0 > 0.f ? o0 : __expf(o0) - 1.f;
        float o1 = a1 * inv + biA.y; o1 = o1 > 0.f ? o1 : __expf(o1) - 1.f;
        float o2 = a2 * inv + biA.z; o2 = o2 > 0.f ? o2 : __expf(o2) - 1.f;
        float o3 = a3 * inv + biA.w; o3 = o3 > 0.f ? o3 : __expf(o3) - 1.f;
        float o4 = a4 * inv + biB.x; o4 = o4 > 0.f ? o4 : __expf(o4) - 1.f;
        float o5 = a5 * inv + biB.y; o5 = o5 > 0.f ? o5 : __expf(o5) - 1.f;
        float o6 = a6 * inv + biB.z; o6 = o6 > 0.f ? o6 : __expf(o6) - 1.f;
        float o7 = a7 * inv + biB.w; o7 = o7 > 0.f ? o7 : __expf(o7) - 1.f;
        uint4 pk;
        pk.x = pk2bf(o0, o1);
        pk.y = pk2bf(o2, o3);
        pk.z = pk2bf(o4, o5);
        pk.w = pk2bf(o6, o7);
        *(uint4*)((char*)hout + (size_t)i * 256 + lofs) = pk;
    }
}

// ---------------- pooling: (graph, split) grid, LDS reduce, few atomics ----------------

__device__ inline float bflo(uint v) { return __builtin_bit_cast(float, v << 16); }
__device__ inline float bfhi(uint v) { return __builtin_bit_cast(float, v & 0xffff0000u); }

__global__ __launch_bounds__(256) void pool_kernel(const uint* __restrict__ h2v,
                                                   const int* __restrict__ batch, int n,
                                                   float* __restrict__ psum) {
    int g = blockIdx.x;
    int t = threadIdx.x;
    int cp = t & 63;
    int sub = (t >> 6) | (blockIdx.y << 2);   // 0..31
    int b, e;
    {
        int lo = 0, hi = n;
        while (lo < hi) { int mid = (lo + hi) >> 1; if (batch[mid] < g) lo = mid + 1; else hi = mid; }
        b = lo;
        lo = 0; hi = n;
        int g1 = g + 1;
        while (lo < hi) { int mid = (lo + hi) >> 1; if (batch[mid] < g1) lo = mid + 1; else hi = mid; }
        e = lo;
    }
    float a0 = 0.f, a1 = 0.f;
    for (int i = b + sub; i < e; i += 32) {
        uint u = h2v[(size_t)i * 64 + cp];
        a0 += bflo(u); a1 += bfhi(u);
    }
    __shared__ float r0[256], r1[256];
    r0[t] = a0; r1[t] = a1;
    __syncthreads();
    if (t < 64) {
        float s0 = r0[t] + r0[t + 64] + r0[t + 128] + r0[t + 192];
        float s1 = r1[t] + r1[t + 64] + r1[t + 128] + r1[t + 192];
        atomicAdd(&psum[g * 128 + 2 * t], s0);
        atomicAdd(&psum[g * 128 + 2 * t + 1], s1);
    }
}

__global__ void final_kernel(const float* __restrict__ psum, const int* __restrict__ batch,
                             int n, const float* __restrict__ lw,
                             const float* __restrict__ lb, float* __restrict__ out) {
    int g = threadIdx.x;
    if (g >= N_GRAPHS) return;
    int b, e;
    {
        int lo = 0, hi = n;
        while (lo < hi) { int mid = (lo + hi) >> 1; if (batch[mid] < g) lo = mid + 1; else hi = mid; }
        b = lo;
        lo = 0; hi = n;
        int g1 = g + 1;
        while (lo < hi) { int mid = (lo + hi) >> 1; if (batch[mid] < g1) lo = mid + 1; else hi = mid; }
        e = lo;
    }
    float invc = 1.f / fmaxf((float)(e - b), 1.f);
    float z[N_CLASSES];
#pragma unroll
    for (int c = 0; c < N_CLASSES; ++c) z[c] = lb[c];
    for (int k = 0; k < 128; ++k) {
        float p = psum[g * 128 + k] * invc;
#pragma unroll
        for (int c = 0; c < N_CLASSES; ++c) z[c] += p * lw[k * N_CLASSES + c];
    }
    float mx = -1e30f;
#pragma unroll
    for (int c = 0; c < N_CLASSES; ++c) {
        z[c] = z[c] > 0.f ? z[c] : expf(z[c]) - 1.f;
        mx = fmaxf(mx, z[c]);
    }
    float s = 0.f;
#pragma unroll
    for (int c = 0; c < N_CLASSES; ++c) s += expf(z[c] - mx);
    float lse = mx + logf(s);
#pragma unroll
    for (int c = 0; c < N_CLASSES; ++c) out[g * N_CLASSES + c] = z[c] - lse;
}

// ---------------- launch ----------------

extern "C" void kernel_launch(void* const* d_in, const int* in_sizes, int n_in,
                              void* d_out, int out_size, void* d_ws, size_t ws_size,
                              hipStream_t stream) {
    const float* x     = (const float*)d_in[0];
    const int*   ei    = (const int*)d_in[1];
    const int*   batch = (const int*)d_in[2];
    const float* Wl    = (const float*)d_in[3];
    const float* Wr    = (const float*)d_in[4];
    const float* bl    = (const float*)d_in[5];
    const float* br    = (const float*)d_in[6];
    const float* att   = (const float*)d_in[7];
    const float* bias  = (const float*)d_in[8];
    const float* lw    = (const float*)d_in[9];
    const float* lb    = (const float*)d_in[10];
    float* out = (float*)d_out;

    const int n = in_sizes[2];         // 50000
    const int E = in_sizes[1] / 2;     // 800000
    const int total_edges = E + n;

    char* ws = (char*)d_ws;
    size_t o = 0;
    auto alloc = [&](size_t bytes) -> void* {
        void* p = ws + o;
        o = (o + bytes + 255) & ~(size_t)255;
        return p;
    };
    int*    row_start = (int*)alloc((size_t)(n + 1) * 4);
    int*    bptr      = (int*)alloc((size_t)NB * 4);
    uint*   bbuf      = (uint*)alloc((size_t)NB * BCAP * 4);
    int*    ssrc      = (int*)alloc((size_t)total_edges * 4);
    ushort* xbf0      = (ushort*)alloc((size_t)n * HID * 2);
    ushort* xlb       = (ushort*)alloc((size_t)n * HID * 2);
    ushort* xrb       = (ushort*)alloc((size_t)n * HID * 2);
    ushort* hbA       = (ushort*)alloc((size_t)n * HID * 2);
    ushort* hbB       = (ushort*)alloc((size_t)n * HID * 2);
    uint*   wt        = (uint*)alloc((size_t)N_LAYERS * 256 * 64 * 4);
    float*  psum      = (float*)alloc((size_t)N_GRAPHS * HID * 4);

    hipMemsetAsync(bptr, 0, (size_t)NB * 4, stream);
    hipMemsetAsync(psum, 0, (size_t)N_GRAPHS * HID * 4, stream);

    int wtot = N_LAYERS * 256 * 64;
    int xqb = (n * 16 + 255) / 256;                       // 3125
    int wb  = (wtot + 255) / 256;                         // 192
    int pb  = (total_edges + ACHUNK - 1) / ACHUNK;        // 208
    setup_kernel<<<xqb + wb + pb, 256, 0, stream>>>(
        x, (uint*)xbf0, n, Wl, Wr, wt, wtot, ei, E, bptr, bbuf, xqb, wb);

    int mblocks = (n + 63) / 64;
    int ablocks = (n + 3) / 4;

    csr_gemm0_kernel<<<NB + mblocks, 256, 0, stream>>>(
        bptr, bbuf, n, row_start, ssrc,
        xbf0, (const ushort*)wt, bl, br, xlb, xrb);

    attn_kernel<<<ablocks, 256, 0, stream>>>((const uint*)xlb, (const uint*)xrb,
                                             att, bias, row_start, ssrc, (uint*)hbA, n);
    gemm_mfma<<<mblocks, 256, 0, stream>>>(hbA, (const ushort*)(wt + (size_t)256 * 64),
                                           bl + HID, br + HID, xlb, xrb, n);
    attn_kernel<<<ablocks, 256, 0, stream>>>((const uint*)xlb, (const uint*)xrb,
                                             att + HID, bias + HID, row_start, ssrc,
                                             (uint*)hbB, n);
    gemm_mfma<<<mblocks, 256, 0, stream>>>(hbB, (const ushort*)(wt + (size_t)2 * 256 * 64),
                                           bl + 2 * HID, br + 2 * HID, xlb, xrb, n);
    attn_kernel<<<ablocks, 256, 0, stream>>>((const uint*)xlb, (const uint*)xrb,
                                             att + 2 * HID, bias + 2 * HID, row_start, ssrc,
                                             (uint*)hbA, n);

    pool_kernel<<<dim3(N_GRAPHS, 8), 256, 0, stream>>>((const uint*)hbA, batch, n, psum);
    final_kernel<<<1, 64, 0, stream>>>(psum, batch, n, lw, lb, out);
}

// Round 2
// 321.962 us; speedup vs baseline: 1.0347x; 1.0347x over previous
//
#include <hip/hip_runtime.h>
#include <hip/hip_bf16.h>
#include <math.h>

#define N_NODES 50000
#define N_EDGES 800000
#define N_GRAPHS 64
#define HID 128
#define N_CLASSES 10
#define N_LAYERS 3
#define NEG_SLOPE 0.2f

#define NB 196        // dst buckets of 256 nodes
#define BCAP 5120     // slots per bucket (mean ~4337, sigma ~66 -> +12 sigma)
#define ACHUNK 4096   // edges per partition block

typedef __attribute__((ext_vector_type(8))) short short8;
typedef __attribute__((ext_vector_type(4))) float f32x4;
typedef __attribute__((ext_vector_type(2))) _Float16 h2;

extern "C" __device__ _Float16 __ocml_exp2_f16(_Float16);

__device__ inline ushort f2bf(float f) {
    uint u = __builtin_bit_cast(uint, f);
    u += 0x7fffu + ((u >> 16) & 1u);      // RNE
    return (ushort)(u >> 16);
}
__device__ inline uint pk2bf(float a, float b) {
    return (uint)f2bf(a) | ((uint)f2bf(b) << 16);
}
__device__ inline h2 pkh(float a, float b) {
    return __builtin_bit_cast(h2, __builtin_amdgcn_cvt_pkrtz(a, b));
}

// ---------------- setup: x/W bf16 prep + edge partition, one launch ----------------

__global__ __launch_bounds__(256) void setup_kernel(
    const float* __restrict__ x, uint* __restrict__ xb, int n,
    const float* __restrict__ Wl, const float* __restrict__ Wr,
    uint* __restrict__ wt, int wtot,
    const int* __restrict__ ei, int E,
    int* __restrict__ bptr, uint* __restrict__ bbuf,
    int xqb, int wb) {
    __shared__ int hcnt[256];
    __shared__ int hexcl[256];
    __shared__ int lofs[256];
    __shared__ int delta[256];
    __shared__ uint stage[ACHUNK];
    int t = threadIdx.x;
    int blk = blockIdx.x;

    if (blk < xqb) {                      // ---- x prep: 1 uint4 (8 floats) per thread
        int j = blk * 256 + t;
        if (j < n * 16) {
            const float4* xp = (const float4*)x + (size_t)j * 2;
            float4 a = xp[0], b = xp[1];
            uint4 o;
            o.x = pk2bf(a.x, a.y); o.y = pk2bf(a.z, a.w);
            o.z = pk2bf(b.x, b.y); o.w = pk2bf(b.z, b.w);
            ((uint4*)xb)[j] = o;
        }
        return;
    }
    blk -= xqb;
    if (blk < wb) {                       // ---- W prep (bf16)
        int i = blk * 256 + t;
        if (i >= wtot) return;
        int kp = i & 63;
        int nn = (i >> 6) & 255;
        int l  = i >> 14;
        const float* W = (nn < 128) ? Wl : Wr;
        int c = nn & 127;
        wt[i] = pk2bf(W[l * 16384 + (2 * kp) * 128 + c],
                      W[l * 16384 + (2 * kp + 1) * 128 + c]);
        return;
    }
    blk -= wb;                            // ---- partition
    int total = E + n;
    int base = blk * ACHUNK;
    int cntblk = min(ACHUNK, total - base);
    hcnt[t] = 0; lofs[t] = 0;
    __syncthreads();

    uint v[16]; int bk[16];
#pragma unroll
    for (int j = 0; j < 16; ++j) {
        int e = base + j * 256 + t;
        bk[j] = -1;
        if (e < total) {
            int s, d;
            if (e < E) { s = ei[e]; d = ei[E + e]; }
            else       { s = e - E; d = e - E; }
            v[j] = ((uint)s << 16) | (uint)d;    // src,dst both < 65536
            bk[j] = d >> 8;
            atomicAdd(&hcnt[bk[j]], 1);
        }
    }
    __syncthreads();
    int hv = hcnt[t];
    __shared__ int stmp[256];
    stmp[t] = hv;
    __syncthreads();
    for (int off = 1; off < 256; off <<= 1) {
        int u = (t >= off) ? stmp[t - off] : 0;
        __syncthreads();
        stmp[t] += u;
        __syncthreads();
    }
    hexcl[t] = stmp[t] - hv;
    __syncthreads();
#pragma unroll
    for (int j = 0; j < 16; ++j) {
        if (bk[j] >= 0) {
            int pos = hexcl[bk[j]] + atomicAdd(&lofs[bk[j]], 1);
            stage[pos] = v[j];
        }
    }
    __syncthreads();
    if (t < NB) {
        int c = hcnt[t];
        int gb = c ? atomicAdd(&bptr[t], c) : 0;
        delta[t] = t * BCAP + gb - hexcl[t];
    }
    __syncthreads();
    for (int idx = t; idx < cntblk; idx += 256) {
        uint val = stage[idx];
        int b = (val >> 8) & 0xff;
        int tgt = delta[b] + idx;
        if (tgt < (b + 1) * BCAP) bbuf[tgt] = val;
    }
}

// ---------------- bucket CSR (blocks 0..NB) + gemm layer 0 (rest), one launch --------
// gemm inputs A,W stay bf16; OUTPUT xl/xr is fp16 (consumed only by attn).

__device__ __forceinline__ void gemm_body(
    const ushort* __restrict__ A, const ushort* __restrict__ Wt,
    const float* __restrict__ bl, const float* __restrict__ br,
    ushort* __restrict__ xlb, ushort* __restrict__ xrb, int n, int bid, int tid) {
    int wv = tid >> 6;
    int lane = tid & 63;
    int q = lane >> 4, m16 = lane & 15;
    int m0 = bid * 64;

    short8 bf[4][4];
#pragma unroll
    for (int nt = 0; nt < 4; ++nt) {
        const ushort* wp = Wt + (size_t)(wv * 64 + nt * 16 + m16) * 128 + q * 8;
#pragma unroll
        for (int ks = 0; ks < 4; ++ks) bf[nt][ks] = *(const short8*)(wp + ks * 32);
    }
    const ushort* ap[4];
#pragma unroll
    for (int mt = 0; mt < 4; ++mt) {
        int r = m0 + mt * 16 + m16;
        if (r > n - 1) r = n - 1;
        ap[mt] = A + (size_t)r * 128 + q * 8;
    }

    f32x4 z = {0.f, 0.f, 0.f, 0.f};
    f32x4 acc[4][4];
#pragma unroll
    for (int mt = 0; mt < 4; ++mt)
#pragma unroll
        for (int nt = 0; nt < 4; ++nt) acc[mt][nt] = z;

#pragma unroll
    for (int ks = 0; ks < 4; ++ks) {
        short8 af[4];
#pragma unroll
        for (int mt = 0; mt < 4; ++mt) af[mt] = *(const short8*)(ap[mt] + ks * 32);
#pragma unroll
        for (int mt = 0; mt < 4; ++mt)
#pragma unroll
            for (int nt = 0; nt < 4; ++nt)
                acc[mt][nt] = __builtin_amdgcn_mfma_f32_16x16x32_bf16(
                    bf[nt][ks], af[mt], acc[mt][nt], 0, 0, 0);
    }

    ushort* outp = (wv >= 2) ? xrb : xlb;
    const float* bx = (wv >= 2) ? br : bl;
    int fb = (wv & 1) * 64;
#pragma unroll
    for (int nt = 0; nt < 4; ++nt) {
        int fcol = fb + nt * 16 + q * 4;
        float4 b4 = *(const float4*)&bx[fcol];
#pragma unroll
        for (int mt = 0; mt < 4; ++mt) {
            int m = m0 + mt * 16 + m16;
            if (m < n) {
                uint2 pk;
                pk.x = __builtin_bit_cast(uint, pkh(acc[mt][nt][0] + b4.x,
                                                    acc[mt][nt][1] + b4.y));
                pk.y = __builtin_bit_cast(uint, pkh(acc[mt][nt][2] + b4.z,
                                                    acc[mt][nt][3] + b4.w));
                *(uint2*)&outp[(size_t)m * 128 + fcol] = pk;
            }
        }
    }
}

__global__ __launch_bounds__(256) void csr_gemm0_kernel(
    const int* __restrict__ bptr, const uint* __restrict__ bbuf, int n,
    int* __restrict__ row_start, int* __restrict__ ssrc,
    const ushort* __restrict__ A, const ushort* __restrict__ Wt,
    const float* __restrict__ bl, const float* __restrict__ br,
    ushort* __restrict__ xlb, ushort* __restrict__ xrb) {
    int t = threadIdx.x;
    if (blockIdx.x >= NB) {
        gemm_body(A, Wt, bl, br, xlb, xrb, n, blockIdx.x - NB, t);
        return;
    }
    int b = blockIdx.x;
    __shared__ int sb[256], h[256], hx[256], lofs[256];
    int bv = (t < NB) ? min(bptr[t], BCAP) : 0;
    sb[t] = bv;
    __syncthreads();
    for (int off = 1; off < 256; off <<= 1) {
        int u = (t >= off) ? sb[t - off] : 0;
        __syncthreads();
        sb[t] += u;
        __syncthreads();
    }
    int cnt = min(bptr[b], BCAP);
    int base = sb[b] - cnt;               // exclusive prefix
    if (b == NB - 1 && t == 0) row_start[n] = sb[NB - 1];
    h[t] = 0; lofs[t] = 0;
    __syncthreads();
    const uint* bp = bbuf + (size_t)b * BCAP;
    for (int k = t; k < cnt; k += 256) atomicAdd(&h[bp[k] & 255u], 1);
    __syncthreads();
    int hv = h[t];
    hx[t] = hv;
    __syncthreads();
    for (int off = 1; off < 256; off <<= 1) {
        int u = (t >= off) ? hx[t - off] : 0;
        __syncthreads();
        hx[t] += u;
        __syncthreads();
    }
    int excl = hx[t] - hv;
    int node = (b << 8) + t;
    if (node < n) row_start[node] = base + excl;
    __syncthreads();
    h[t] = excl;
    __syncthreads();
    for (int k = t; k < cnt; k += 256) {
        uint val = bp[k];
        int dl = val & 255u;
        int pos = base + h[dl] + atomicAdd(&lofs[dl], 1);
        ssrc[pos] = (int)((val & 0xffff0000u) >> 8);   // src*256 byte offset
    }
}

__global__ __launch_bounds__(256) void gemm_mfma(
    const ushort* __restrict__ A, const ushort* __restrict__ Wt,
    const float* __restrict__ bl, const float* __restrict__ br,
    ushort* __restrict__ xlb, ushort* __restrict__ xrb, int n) {
    gemm_body(A, Wt, bl, br, xlb, xrb, n, blockIdx.x, threadIdx.x);
}

// ---------------- fused attention: node-per-16-lane-group, uniform predicated loop ----
// Each 16-lane group owns ONE node (4 nodes/wave, 16/block). Lane holds 8 channels.
// Head sums are the 4-lane DPP quad_perm tree; the per-head denominator is complete
// per lane -> NO cross-group reduction, NO multi-tier epilogue. Loop count is the
// wave-max degree; invalid slots clamp the load and zero the weight. Next iteration's
// ssrc values are prefetched so the ssrc->gather latency chain is split.
// Scores keep the built-in -8 shift (EINIT {-1,-1}/lane summed over 4 lanes) so exp2
// weights stay small; the 2^-8 cancels in the softmax division.

#define ESCORE(u, v01, v23, v45, v67, es)                  \
    h2 v01 = __builtin_bit_cast(h2, u.x);                  \
    h2 v23 = __builtin_bit_cast(h2, u.y);                  \
    h2 v45 = __builtin_bit_cast(h2, u.z);                  \
    h2 v67 = __builtin_bit_cast(h2, u.w);                  \
    _Float16 es;                                           \
    {                                                      \
        h2 t01 = v01 + xr01, t23 = v23 + xr23;             \
        h2 t45 = v45 + xr45, t67 = v67 + xr67;             \
        t01 = __builtin_elementwise_max(t01, t01 * K02);   \
        t23 = __builtin_elementwise_max(t23, t23 * K02);   \
        t45 = __builtin_elementwise_max(t45, t45 * K02);   \
        t67 = __builtin_elementwise_max(t67, t67 * K02);   \
        h2 eh = EINIT + at01 * t01;                        \
        eh += at23 * t23;                                  \
        eh += at45 * t45;                                  \
        eh += at67 * t67;                                  \
        es = eh.x + eh.y;                                  \
    }

template <int CTRL>
__device__ inline uint dpp_add_h2(uint q) {   // q += quad_perm<CTRL>(q), packed f16
    uint r = (uint)__builtin_amdgcn_mov_dpp((int)q, CTRL, 0xF, 0xF, true);
    h2 s = __builtin_bit_cast(h2, q) + __builtin_bit_cast(h2, r);
    return __builtin_bit_cast(uint, s);
}

__global__ __launch_bounds__(256) void attn_kernel(
    const uint* __restrict__ xlb, const uint* __restrict__ xrb,
    const float* __restrict__ att, const float* __restrict__ bias,
    const int* __restrict__ row_start, const int* __restrict__ ssrc,
    uint* __restrict__ hout, int n) {
    int wave = threadIdx.x >> 6;
    int lane = threadIdx.x & 63;
    int g    = lane >> 4;          // node slot within wave
    int l16  = lane & 15;          // channel-slice lane: ch 8*l16 .. 8*l16+7
    int i0n  = blockIdx.x * 16 + wave * 4 + g;
    int i    = min(i0n, n - 1);

    const char* xlB = (const char*)xlb;
    uint lofs = (uint)l16 * 16;

    uint4 xru = *(const uint4*)((const char*)xrb + (size_t)i * 256 + lofs);
    h2 xr01 = __builtin_bit_cast(h2, xru.x);
    h2 xr23 = __builtin_bit_cast(h2, xru.y);
    h2 xr45 = __builtin_bit_cast(h2, xru.z);
    h2 xr67 = __builtin_bit_cast(h2, xru.w);
    const float L2E = 1.4426950408889634f;
    float4 atA = ((const float4*)att)[l16 * 2];
    float4 atB = ((const float4*)att)[l16 * 2 + 1];
    h2 at01 = pkh(atA.x * L2E, atA.y * L2E);
    h2 at23 = pkh(atA.z * L2E, atA.w * L2E);
    h2 at45 = pkh(atB.x * L2E, atB.y * L2E);
    h2 at67 = pkh(atB.z * L2E, atB.w * L2E);
    const h2 K02   = {(_Float16)0.2f, (_Float16)0.2f};
    const h2 EINIT = {(_Float16)-1.0f, (_Float16)-1.0f};   // -2/lane * 4 lanes = -8

    int p0 = row_start[i], p1 = row_start[i + 1];
    int d = p1 - p0;                        // >= 1 (self loop)
    int m = max(d, __shfl_xor(d, 16));
    m = max(m, __shfl_xor(m, 32));
    int iters = (m + 3) >> 2;               // wave-uniform
    int lst = p1 - 1;

    _Float16 denA = (_Float16)0.f, denB = (_Float16)0.f;
    h2 aE01 = {0, 0}, aE23 = {0, 0}, aE45 = {0, 0}, aE67 = {0, 0};  // even slots
    h2 aO01 = {0, 0}, aO23 = {0, 0}, aO45 = {0, 0}, aO67 = {0, 0};  // odd slots

    int idx = p0;
    uint s0 = (uint)ssrc[idx];
    uint s1 = (uint)ssrc[min(idx + 1, lst)];
    uint s2 = (uint)ssrc[min(idx + 2, lst)];
    uint s3 = (uint)ssrc[min(idx + 3, lst)];

    for (int it = 0; it < iters; ++it) {
        uint4 u0 = *(const uint4*)(xlB + s0 + lofs);
        uint4 u1 = *(const uint4*)(xlB + s1 + lofs);
        uint4 u2 = *(const uint4*)(xlB + s2 + lofs);
        uint4 u3 = *(const uint4*)(xlB + s3 + lofs);
        bool b0 = idx     < p1;
        bool b1 = idx + 1 < p1;
        bool b2 = idx + 2 < p1;
        bool b3 = idx + 3 < p1;
        int nidx = idx + 4;
        uint ns0 = (uint)ssrc[min(nidx,     lst)];   // prefetch next iteration
        uint ns1 = (uint)ssrc[min(nidx + 1, lst)];
        uint ns2 = (uint)ssrc[min(nidx + 2, lst)];
        uint ns3 = (uint)ssrc[min(nidx + 3, lst)];
        ESCORE(u0, v001, v023, v045, v067, es0);
        ESCORE(u1, v101, v123, v145, v167, es1);
        ESCORE(u2, v201, v223, v245, v267, es2);
        ESCORE(u3, v301, v323, v345, v367, es3);
        h2 q01h; q01h.x = es0; q01h.y = es1;
        h2 q23h; q23h.x = es2; q23h.y = es3;
        uint q01 = __builtin_bit_cast(uint, q01h);
        uint q23 = __builtin_bit_cast(uint, q23h);
        q01 = dpp_add_h2<0xB1>(q01);   // xor 1 (quad_perm [1,0,3,2])
        q23 = dpp_add_h2<0xB1>(q23);
        q01 = dpp_add_h2<0x4E>(q01);   // xor 2 (quad_perm [2,3,0,1])
        q23 = dpp_add_h2<0x4E>(q23);
        h2 e01 = __builtin_bit_cast(h2, q01);
        h2 e23 = __builtin_bit_cast(h2, q23);
        const _Float16 zh = (_Float16)0.f;
        _Float16 w0 = b0 ? __ocml_exp2_f16(e01.x) : zh;
        _Float16 w1 = b1 ? __ocml_exp2_f16(e01.y) : zh;
        _Float16 w2 = b2 ? __ocml_exp2_f16(e23.x) : zh;
        _Float16 w3 = b3 ? __ocml_exp2_f16(e23.y) : zh;
        denA += w0; denB += w1; denA += w2; denB += w3;
        h2 wA = {w0, w0}, wB = {w1, w1}, wC = {w2, w2}, wD = {w3, w3};
        aE01 += wA * v001; aE23 += wA * v023; aE45 += wA * v045; aE67 += wA * v067;
        aO01 += wB * v101; aO23 += wB * v123; aO45 += wB * v145; aO67 += wB * v167;
        aE01 += wC * v201; aE23 += wC * v223; aE45 += wC * v245; aE67 += wC * v267;
        aO01 += wD * v301; aO23 += wD * v323; aO45 += wD * v345; aO67 += wD * v367;
        idx = nidx; s0 = ns0; s1 = ns1; s2 = ns2; s3 = ns3;
    }

    // per-lane state is complete: no cross-lane reduce needed
    float den = (float)denA + (float)denB;
    float inv = 1.f / den;
    h2 a01 = aE01 + aO01;
    h2 a23 = aE23 + aO23;
    h2 a45 = aE45 + aO45;
    h2 a67 = aE67 + aO67;
    float4 biA = ((const float4*)bias)[l16 * 2];
    float4 biB = ((const float4*)bias)[l16 * 2 + 1];
    float o0 = (float)a01.x * inv + biA.x; o0 = o0 > 0.f ? o0 : __expf(o0) - 1.f;
    float o1 = (float)a01.y * inv + biA.y; o1 = o1 > 0.f ? o1 : __expf(o1) - 1.f;
    float o2 = (float)a23.x * inv + biA.z; o2 = o2 > 0.f ? o2 : __expf(o2) - 1.f;
    float o3 = (float)a23.y * inv + biA.w; o3 = o3 > 0.f ? o3 : __expf(o3) - 1.f;
    float o4 = (float)a45.x * inv + biB.x; o4 = o4 > 0.f ? o4 : __expf(o4) - 1.f;
    float o5 = (float)a45.y * inv + biB.y; o5 = o5 > 0.f ? o5 : __expf(o5) - 1.f;
    float o6 = (float)a67.x * inv + biB.z; o6 = o6 > 0.f ? o6 : __expf(o6) - 1.f;
    float o7 = (float)a67.y * inv + biB.w; o7 = o7 > 0.f ? o7 : __expf(o7) - 1.f;
    if (i0n < n) {
        uint4 pk;
        pk.x = pk2bf(o0, o1);
        pk.y = pk2bf(o2, o3);
        pk.z = pk2bf(o4, o5);
        pk.w = pk2bf(o6, o7);
        *(uint4*)((char*)hout + (size_t)i * 256 + lofs) = pk;
    }
}

// ---------------- pooling: (graph, split) grid, LDS reduce, few atomics ----------------

__device__ inline float bflo(uint v) { return __builtin_bit_cast(float, v << 16); }
__device__ inline float bfhi(uint v) { return __builtin_bit_cast(float, v & 0xffff0000u); }

__global__ __launch_bounds__(256) void pool_kernel(const uint* __restrict__ h2v,
                                                   const int* __restrict__ batch, int n,
                                                   float* __restrict__ psum) {
    int g = blockIdx.x;
    int t = threadIdx.x;
    int cp = t & 63;
    int sub = (t >> 6) | (blockIdx.y << 2);   // 0..31
    int b, e;
    {
        int lo = 0, hi = n;
        while (lo < hi) { int mid = (lo + hi) >> 1; if (batch[mid] < g) lo = mid + 1; else hi = mid; }
        b = lo;
        lo = 0; hi = n;
        int g1 = g + 1;
        while (lo < hi) { int mid = (lo + hi) >> 1; if (batch[mid] < g1) lo = mid + 1; else hi = mid; }
        e = lo;
    }
    float a0 = 0.f, a1 = 0.f;
    for (int i = b + sub; i < e; i += 32) {
        uint u = h2v[(size_t)i * 64 + cp];
        a0 += bflo(u); a1 += bfhi(u);
    }
    __shared__ float r0[256], r1[256];
    r0[t] = a0; r1[t] = a1;
    __syncthreads();
    if (t < 64) {
        float s0 = r0[t] + r0[t + 64] + r0[t + 128] + r0[t + 192];
        float s1 = r1[t] + r1[t + 64] + r1[t + 128] + r1[t + 192];
        atomicAdd(&psum[g * 128 + 2 * t], s0);
        atomicAdd(&psum[g * 128 + 2 * t + 1], s1);
    }
}

__global__ void final_kernel(const float* __restrict__ psum, const int* __restrict__ batch,
                             int n, const float* __restrict__ lw,
                             const float* __restrict__ lb, float* __restrict__ out) {
    int g = threadIdx.x;
    if (g >= N_GRAPHS) return;
    int b, e;
    {
        int lo = 0, hi = n;
        while (lo < hi) { int mid = (lo + hi) >> 1; if (batch[mid] < g) lo = mid + 1; else hi = mid; }
        b = lo;
        lo = 0; hi = n;
        int g1 = g + 1;
        while (lo < hi) { int mid = (lo + hi) >> 1; if (batch[mid] < g1) lo = mid + 1; else hi = mid; }
        e = lo;
    }
    float invc = 1.f / fmaxf((float)(e - b), 1.f);
    float z[N_CLASSES];
#pragma unroll
    for (int c = 0; c < N_CLASSES; ++c) z[c] = lb[c];
    for (int k = 0; k < 128; ++k) {
        float p = psum[g * 128 + k] * invc;
#pragma unroll
        for (int c = 0; c < N_CLASSES; ++c) z[c] += p * lw[k * N_CLASSES + c];
    }
    float mx = -1e30f;
#pragma unroll
    for (int c = 0; c < N_CLASSES; ++c) {
        z[c] = z[c] > 0.f ? z[c] : expf(z[c]) - 1.f;
        mx = fmaxf(mx, z[c]);
    }
    float s = 0.f;
#pragma unroll
    for (int c = 0; c < N_CLASSES; ++c) s += expf(z[c] - mx);
    float lse = mx + logf(s);
#pragma unroll
    for (int c = 0; c < N_CLASSES; ++c) out[g * N_CLASSES + c] = z[c] - lse;
}

// ---------------- launch ----------------

extern "C" void kernel_launch(void* const* d_in, const int* in_sizes, int n_in,
                              void* d_out, int out_size, void* d_ws, size_t ws_size,
                              hipStream_t stream) {
    const float* x     = (const float*)d_in[0];
    const int*   ei    = (const int*)d_in[1];
    const int*   batch = (const int*)d_in[2];
    const float* Wl    = (const float*)d_in[3];
    const float* Wr    = (const float*)d_in[4];
    const float* bl    = (const float*)d_in[5];
    const float* br    = (const float*)d_in[6];
    const float* att   = (const float*)d_in[7];
    const float* bias  = (const float*)d_in[8];
    const float* lw    = (const float*)d_in[9];
    const float* lb    = (const float*)d_in[10];
    float* out = (float*)d_out;

    const int n = in_sizes[2];         // 50000
    const int E = in_sizes[1] / 2;     // 800000
    const int total_edges = E + n;

    char* ws = (char*)d_ws;
    size_t o = 0;
    auto alloc = [&](size_t bytes) -> void* {
        void* p = ws + o;
        o = (o + bytes + 255) & ~(size_t)255;
        return p;
    };
    int*    row_start = (int*)alloc((size_t)(n + 1) * 4);
    int*    bptr      = (int*)alloc((size_t)NB * 4);
    uint*   bbuf      = (uint*)alloc((size_t)NB * BCAP * 4);
    int*    ssrc      = (int*)alloc((size_t)total_edges * 4);
    ushort* xbf0      = (ushort*)alloc((size_t)n * HID * 2);
    ushort* xlb       = (ushort*)alloc((size_t)n * HID * 2);
    ushort* xrb       = (ushort*)alloc((size_t)n * HID * 2);
    ushort* hbA       = (ushort*)alloc((size_t)n * HID * 2);
    ushort* hbB       = (ushort*)alloc((size_t)n * HID * 2);
    uint*   wt        = (uint*)alloc((size_t)N_LAYERS * 256 * 64 * 4);
    float*  psum      = (float*)alloc((size_t)N_GRAPHS * HID * 4);

    hipMemsetAsync(bptr, 0, (size_t)NB * 4, stream);
    hipMemsetAsync(psum, 0, (size_t)N_GRAPHS * HID * 4, stream);

    int wtot = N_LAYERS * 256 * 64;
    int xqb = (n * 16 + 255) / 256;                       // 3125
    int wb  = (wtot + 255) / 256;                         // 192
    int pb  = (total_edges + ACHUNK - 1) / ACHUNK;        // 208
    setup_kernel<<<xqb + wb + pb, 256, 0, stream>>>(
        x, (uint*)xbf0, n, Wl, Wr, wt, wtot, ei, E, bptr, bbuf, xqb, wb);

    int mblocks = (n + 63) / 64;
    int ablocks = (n + 15) / 16;

    csr_gemm0_kernel<<<NB + mblocks, 256, 0, stream>>>(
        bptr, bbuf, n, row_start, ssrc,
        xbf0, (const ushort*)wt, bl, br, xlb, xrb);

    attn_kernel<<<ablocks, 256, 0, stream>>>((const uint*)xlb, (const uint*)xrb,
                                             att, bias, row_start, ssrc, (uint*)hbA, n);
    gemm_mfma<<<mblocks, 256, 0, stream>>>(hbA, (const ushort*)(wt + (size_t)256 * 64),
                                           bl + HID, br + HID, xlb, xrb, n);
    attn_kernel<<<ablocks, 256, 0, stream>>>((const uint*)xlb, (const uint*)xrb,
                                             att + HID, bias + HID, row_start, ssrc,
                                             (uint*)hbB, n);
    gemm_mfma<<<mblocks, 256, 0, stream>>>(hbB, (const ushort*)(wt + (size_t)2 * 256 * 64),
                                           bl + 2 * HID, br + 2 * HID, xlb, xrb, n);
    attn_kernel<<<ablocks, 256, 0, stream>>>((const uint*)xlb, (const uint*)xrb,
                                             att + 2 * HID, bias + 2 * HID, row_start, ssrc,
                                             (uint*)hbA, n);

    pool_kernel<<<dim3(N_GRAPHS, 8), 256, 0, stream>>>((const uint*)hbA, batch, n, psum);
    final_kernel<<<1, 64, 0, stream>>>(psum, batch, n, lw, lb, out);
}